// Round 3
// baseline (134.316 us; speedup 1.0000x reference)
//
#include <hip/hip_runtime.h>
#include <hip/hip_bf16.h>

#define N_NODES 50000
#define HDIM    256
#define CDIM    32
#define JDIM    96   // C*3 output elements per node
#define NB      64   // nodes per block
#define HP      128  // h-values staged in LDS per pass (2 passes)
#define NW      8    // waves per block
#define CH      4    // channels per wave (NW*CH == CDIM)

// Weight load at a WAVE-UNIFORM index i -> compiler emits scalar s_load.
template<bool ISBF>
__device__ __forceinline__ float ldw(const void* __restrict__ p, int i) {
    if constexpr (ISBF) {
        unsigned int d = ((const unsigned int*)p)[i >> 1];
        return __uint_as_float((i & 1) ? (d & 0xffff0000u) : (d << 16));
    } else {
        return ((const float*)p)[i];
    }
}

// Per-lane load (pos only).
template<bool ISBF>
__device__ __forceinline__ float ldv(const void* __restrict__ p, int i) {
    if constexpr (ISBF) return __bfloat162float(((const __hip_bfloat16*)p)[i]);
    else                return ((const float*)p)[i];
}

// out[n, c*3+k] = sum_h W2[h,c] * sech^2(z[n,h]) * W1[k,h]
// Block: 512 threads = 8 waves. Wave w owns channels [4w, 4w+4); lane = node.
// Phase 1: S[h][node] = sech^2(z) in LDS, computed once per block.
// Phase 2: depth-1 software pipeline over groups of 4 h; weights via the
// scalar path (s_load), S via one stride-1 ds_read_b32 per h.
template<bool ISBF>
__device__ __forceinline__ void run_impl(
    const void* __restrict__ pos,
    const void* __restrict__ W1,
    const void* __restrict__ b1,
    const void* __restrict__ W2,
    void* __restrict__ out,
    float (*S)[NB])
{
    const int tid = threadIdx.x;
    const int w   = __builtin_amdgcn_readfirstlane(tid >> 6);  // wave id, uniform
    const int l   = tid & 63;
    const int n   = blockIdx.x * NB + l;
    const bool ok = (n < N_NODES);

    float p0 = 0.f, p1 = 0.f, p2 = 0.f;
    if (ok) {
        p0 = ldv<ISBF>(pos, n * 3 + 0);
        p1 = ldv<ISBF>(pos, n * 3 + 1);
        p2 = ldv<ISBF>(pos, n * 3 + 2);
    }

    float acc[3 * CH];
#pragma unroll
    for (int j = 0; j < 3 * CH; ++j) acc[j] = 0.0f;

    const int c0 = w * CH;

    for (int pass = 0; pass < 2; ++pass) {
        const int hbase = pass * HP;

        // ---- phase 1: each wave computes HP/NW = 16 rows of S ----
        {
            const int h0 = hbase + w * (HP / NW);
#pragma unroll
            for (int i = 0; i < HP / NW; ++i) {
                const int h = h0 + i;
                float zb = ldw<ISBF>(b1, h);                 // scalar
                float wx = ldw<ISBF>(W1, 0 * HDIM + h);      // scalar
                float wy = ldw<ISBF>(W1, 1 * HDIM + h);      // scalar
                float wz = ldw<ISBF>(W1, 2 * HDIM + h);      // scalar
                float z  = fmaf(p0, wx, fmaf(p1, wy, fmaf(p2, wz, zb)));
                // sech^2(z) = 4u/(1+u)^2, u = e^{-2|z|}: branch-free, no overflow
                float u   = __expf(-2.0f * fabsf(z));
                float inv = __builtin_amdgcn_rcpf(1.0f + u);
                S[h - hbase][l] = 4.0f * u * inv * inv;      // stride-1 write
            }
        }
        __syncthreads();

        // ---- phase 2: depth-1 pipelined accumulation over HP h-values ----
        {
            float bwx[2][4], bwy[2][4], bwz[2][4], bw2[2][4][CH], bs[2][4];

#define LOADG(buf, g)                                                         \
            do {                                                              \
                const int hh = hbase + (g) * 4;                               \
                _Pragma("unroll")                                             \
                for (int j = 0; j < 4; ++j) {                                 \
                    bwx[buf][j] = ldw<ISBF>(W1, 0 * HDIM + hh + j);           \
                    bwy[buf][j] = ldw<ISBF>(W1, 1 * HDIM + hh + j);           \
                    bwz[buf][j] = ldw<ISBF>(W1, 2 * HDIM + hh + j);           \
                    bs[buf][j]  = S[(g) * 4 + j][l];                          \
                    _Pragma("unroll")                                         \
                    for (int q = 0; q < CH; ++q)                              \
                        bw2[buf][j][q] = ldw<ISBF>(W2, (hh + j) * CDIM + c0 + q); \
                }                                                             \
            } while (0)

            LOADG(0, 0);
#pragma unroll
            for (int g = 0; g < HP / 4; ++g) {     // fully unrolled: static idx
                const int cur = g & 1, nxt = cur ^ 1;
                if (g + 1 < HP / 4) LOADG(nxt, g + 1);
#pragma unroll
                for (int j = 0; j < 4; ++j) {
                    float s  = bs[cur][j];
                    float a0 = s * bwx[cur][j];
                    float a1 = s * bwy[cur][j];
                    float a2 = s * bwz[cur][j];
#pragma unroll
                    for (int q = 0; q < CH; ++q) {
                        float ww = bw2[cur][j][q];
                        acc[q * 3 + 0] = fmaf(a0, ww, acc[q * 3 + 0]);
                        acc[q * 3 + 1] = fmaf(a1, ww, acc[q * 3 + 1]);
                        acc[q * 3 + 2] = fmaf(a2, ww, acc[q * 3 + 2]);
                    }
                }
            }
#undef LOADG
        }
        if (pass == 0) __syncthreads();   // protect S before pass-1 overwrite
    }

    if (!ok) return;

    if constexpr (ISBF) {
        // 12 bf16 = 6 dwords = 3 x uint2 (8B-aligned: offset 24B * w).
        unsigned int pk[6];
#pragma unroll
        for (int j = 0; j < 12; j += 2) {
            unsigned short lo = __hip_bfloat16_raw(__float2bfloat16(acc[j])).x;
            unsigned short hi = __hip_bfloat16_raw(__float2bfloat16(acc[j + 1])).x;
            pk[j >> 1] = ((unsigned int)hi << 16) | lo;
        }
        uint2* op = (uint2*)((__hip_bfloat16*)out + (size_t)n * JDIM + c0 * 3);
#pragma unroll
        for (int j = 0; j < 3; ++j)
            op[j] = make_uint2(pk[2 * j], pk[2 * j + 1]);
    } else {
        // 12 f32 = 3 x float4 (16B-aligned: offset 48B * w).
        float4* op = (float4*)((float*)out + (size_t)n * JDIM + c0 * 3);
#pragma unroll
        for (int j = 0; j < 3; ++j)
            op[j] = make_float4(acc[4 * j], acc[4 * j + 1], acc[4 * j + 2], acc[4 * j + 3]);
    }
}

__global__ __launch_bounds__(512, 6) void grad_fused(
    const void* __restrict__ pos,
    const void* __restrict__ W1,
    const void* __restrict__ b1,
    const void* __restrict__ W2,
    void* __restrict__ out)
{
    __shared__ float S[HP][NB];   // 32 KiB

    // ---- runtime dtype detection (wave-uniform, identical across waves) ----
    unsigned short uw = ((const unsigned short*)pos)[threadIdx.x & 63];
    int ef = (uw >> 7) & 0xFF;
    unsigned long long bal = __ballot(ef >= 100 && ef <= 140);
    const bool isbf = __popcll(bal) >= 56;

    if (isbf) run_impl<true >(pos, W1, b1, W2, out, S);
    else      run_impl<false>(pos, W1, b1, W2, out, S);
}

extern "C" void kernel_launch(void* const* d_in, const int* in_sizes, int n_in,
                              void* d_out, int out_size, void* d_ws, size_t ws_size,
                              hipStream_t stream) {
    (void)d_ws; (void)ws_size; (void)in_sizes; (void)n_in; (void)out_size;
    const void* pos = d_in[0];  // [N,3]
    const void* W1  = d_in[1];  // [3,H]
    const void* b1  = d_in[2];  // [H]
    const void* W2  = d_in[3];  // [H,C]

    int block = 512;             // 8 waves
    int grid = (N_NODES + NB - 1) / NB;  // 782 blocks
    grad_fused<<<grid, block, 0, stream>>>(pos, W1, b1, W2, d_out);
}